// Round 9
// baseline (428.048 us; speedup 1.0000x reference)
//
#include <hip/hip_runtime.h>

#define NN 30000
#define NE 300000
#define D_IN 256
#define D_H 128
#define D_OUT 64
#define NL 6

typedef unsigned short ushort_t;
typedef unsigned int uint_t;
typedef __attribute__((ext_vector_type(8))) short sh8;
typedef __attribute__((ext_vector_type(4))) float f4;

// fp32 -> bf16 round-to-nearest-even
static __device__ __forceinline__ ushort_t f2bf(float f) {
    uint_t u = __float_as_uint(f);
    u = (u + 0x7FFFu + ((u >> 16) & 1u)) >> 16;
    return (ushort_t)u;
}
static __device__ __forceinline__ float bflo(uint_t u) { return __uint_as_float(u << 16); }
static __device__ __forceinline__ float bfhi(uint_t u) { return __uint_as_float(u & 0xFFFF0000u); }

// ---------------------------------------------------------------------------
__global__ void degree_kernel(const int* __restrict__ src, const int* __restrict__ dst,
                              int* __restrict__ outdeg, int* __restrict__ indeg) {
    int e = blockIdx.x * blockDim.x + threadIdx.x;
    if (e < NE) {
        atomicAdd(&outdeg[src[e]], 1);
        atomicAdd(&indeg[dst[e]], 1);
    }
}

__global__ void rsqrt_kernel(const int* __restrict__ deg, float* __restrict__ inv, int n) {
    int i = blockIdx.x * blockDim.x + threadIdx.x;
    if (i < n) {
        float d = (float)deg[i];
        inv[i] = rsqrtf(d < 1.0f ? 1.0f : d);
    }
}

// exclusive prefix scan of deg[NN] -> ptr[NN+1]
__global__ __launch_bounds__(1024) void scan_kernel(const int* __restrict__ deg,
                                                    int* __restrict__ ptr) {
    __shared__ int wsum[16];
    __shared__ int chunk_base;
    if (threadIdx.x == 0) chunk_base = 0;
    __syncthreads();
    const int lane = threadIdx.x & 63;
    const int wid = threadIdx.x >> 6;
    for (int base = 0; base < NN; base += 1024) {
        int i = base + threadIdx.x;
        int v = (i < NN) ? deg[i] : 0;
        int s = v;
#pragma unroll
        for (int off = 1; off < 64; off <<= 1) {
            int t = __shfl_up(s, off, 64);
            if (lane >= off) s += t;
        }
        if (lane == 63) wsum[wid] = s;
        __syncthreads();
        if (wid == 0 && lane < 16) {
            int ws = wsum[lane];
#pragma unroll
            for (int off = 1; off < 16; off <<= 1) {
                int t = __shfl_up(ws, off, 64);
                if (lane >= off) ws += t;
            }
            wsum[lane] = ws;
        }
        __syncthreads();
        int cb = chunk_base;
        int woff = (wid > 0) ? wsum[wid - 1] : 0;
        if (i < NN) ptr[i] = cb + woff + s - v;
        int total = wsum[15];
        __syncthreads();
        if (threadIdx.x == 0) chunk_base = cb + total;
        __syncthreads();
    }
    if (threadIdx.x == 0) ptr[NN] = chunk_base;
}

__global__ void fill_kernel(const int* __restrict__ src, const int* __restrict__ dst,
                            const int* __restrict__ row_ptr, int* __restrict__ cursor,
                            int* __restrict__ col) {
    int e = blockIdx.x * blockDim.x + threadIdx.x;
    if (e < NE) {
        int d = dst[e];
        int pos = atomicAdd(&cursor[d], 1);
        col[row_ptr[d] + pos] = src[e];
    }
}

// ---------------------------------------------------------------------------
// feats fp32 -> bf16 (flat)
__global__ void featconv_kernel(const float* __restrict__ F, ushort_t* __restrict__ Fb) {
    int i = blockIdx.x * blockDim.x + threadIdx.x;   // over NN*256/8
    if (i >= NN * D_IN / 8) return;
    float4 a = *(const float4*)(F + (size_t)i * 8);
    float4 b = *(const float4*)(F + (size_t)i * 8 + 4);
    uint4 o;
    o.x = (uint_t)f2bf(a.x) | ((uint_t)f2bf(a.y) << 16);
    o.y = (uint_t)f2bf(a.z) | ((uint_t)f2bf(a.w) << 16);
    o.z = (uint_t)f2bf(b.x) | ((uint_t)f2bf(b.y) << 16);
    o.w = (uint_t)f2bf(b.z) | ((uint_t)f2bf(b.w) << 16);
    *(uint4*)(Fb + (size_t)i * 8) = o;
}

// p fp32 [NN,64] -> bf16
__global__ void pconv_kernel(const float* __restrict__ P, ushort_t* __restrict__ Pb) {
    int i = blockIdx.x * blockDim.x + threadIdx.x;   // over NN*64/8
    if (i >= NN * D_OUT / 8) return;
    float4 a = *(const float4*)(P + (size_t)i * 8);
    float4 b = *(const float4*)(P + (size_t)i * 8 + 4);
    uint4 o;
    o.x = (uint_t)f2bf(a.x) | ((uint_t)f2bf(a.y) << 16);
    o.y = (uint_t)f2bf(a.z) | ((uint_t)f2bf(a.w) << 16);
    o.z = (uint_t)f2bf(b.x) | ((uint_t)f2bf(b.y) << 16);
    o.w = (uint_t)f2bf(b.z) | ((uint_t)f2bf(b.w) << 16);
    *(uint4*)(Pb + (size_t)i * 8) = o;
}

// ---------------------------------------------------------------------------
// Pack all weights into MFMA B-fragment order, bf16.
// Fragment f (= ct*KF + kt), lane l, j=0..7 holds
//   W[kt*32 + (l>>4)*8 + j][ct*16 + (l&15)]
// ---------------------------------------------------------------------------
__global__ void packw_kernel(const float* __restrict__ W0,
                             const float* __restrict__ Wh,
                             const float* __restrict__ Wout,
                             ushort_t* __restrict__ W0p,
                             ushort_t* __restrict__ Whp,
                             ushort_t* __restrict__ Woutp) {
    int g = blockIdx.x * blockDim.x + threadIdx.x;
    int frag = g >> 6;
    int lane = g & 63;
    if (frag >= 368) return;
    const float* srcw;
    ushort_t* dstp;
    int fl, KF, M;
    if (frag < 64) {                     // W0
        fl = frag; KF = 8; M = 128;
        srcw = W0;
        dstp = W0p;
    } else if (frag < 64 + 192) {        // Wh
        int f2 = frag - 64;
        int l = f2 / 32; fl = f2 % 32; KF = 4; M = 128;
        srcw = Wh + (size_t)l * D_H * D_H;
        dstp = Whp + (size_t)l * 32 * 512;
    } else {                             // Wout blocks
        int f2 = frag - 256;
        int l = f2 / 16; fl = f2 % 16; KF = 4; M = 64;
        srcw = Wout + (size_t)l * D_H * D_OUT;
        dstp = Woutp + (size_t)l * 16 * 512;
    }
    int ct = fl / KF;
    int kt = fl % KF;
    int krow = kt * 32 + (lane >> 4) * 8;
    int cidx = ct * 16 + (lane & 15);
    ushort_t tmp[8];
#pragma unroll
    for (int j = 0; j < 8; j++)
        tmp[j] = f2bf(srcw[(size_t)(krow + j) * M + cidx]);
    uint4 o;
    o.x = (uint_t)tmp[0] | ((uint_t)tmp[1] << 16);
    o.y = (uint_t)tmp[2] | ((uint_t)tmp[3] << 16);
    o.z = (uint_t)tmp[4] | ((uint_t)tmp[5] << 16);
    o.w = (uint_t)tmp[6] | ((uint_t)tmp[7] << 16);
    *(uint4*)(dstp + (size_t)fl * 512 + lane * 8) = o;
}

// ---------------------------------------------------------------------------
// Layer-0 MFMA GEMM (bf16 in, no LDS): Tb = bf16((Fb @ W0) * inv_out)
// block = 4 waves = 2 rg x 2 cgrp over 32 rows (A loads are streamed, cheap).
// ---------------------------------------------------------------------------
__global__ __launch_bounds__(256) void gemm0_mfma(
    const ushort_t* __restrict__ Xb,    // [NN,256] bf16
    const ushort_t* __restrict__ W1p,   // packed, KF=8
    const float* __restrict__ scale,
    ushort_t* __restrict__ Tb)
{
    constexpr int KF = 8;
    constexpr int K = 256;
    const int lane = threadIdx.x & 63;
    const int w = threadIdx.x >> 6;
    const int rg = w >> 1;
    const int cgrp = w & 1;
    const int row0 = blockIdx.x * 32 + rg * 16;

    int arow = row0 + (lane & 15);
    if (arow >= NN) arow = NN - 1;
    const ushort_t* xr = Xb + (size_t)arow * K + ((lane >> 4) * 8);
    sh8 a[KF];
#pragma unroll
    for (int kt = 0; kt < KF; kt++)
        a[kt] = *(const sh8*)(xr + kt * 32);

    const int crow0 = row0 + (lane >> 4) * 4;
    float s[4];
#pragma unroll
    for (int r = 0; r < 4; r++) {
        int rw = crow0 + r;
        s[r] = scale[rw < NN ? rw : NN - 1];
    }
#pragma unroll
    for (int i = 0; i < 4; i++) {
        int ct = cgrp * 4 + i;
        f4 acc = {0.f, 0.f, 0.f, 0.f};
        const ushort_t* wp = W1p + ((size_t)(ct * KF) << 9) + lane * 8;
#pragma unroll
        for (int kt = 0; kt < KF; kt++)
            acc = __builtin_amdgcn_mfma_f32_16x16x32_bf16(
                a[kt], *(const sh8*)(wp + ((size_t)kt << 9)), acc, 0, 0, 0);
        int colb = ct * 16 + (lane & 15);
#pragma unroll
        for (int r = 0; r < 4; r++) {
            int rw = crow0 + r;
            if (rw < NN)
                Tb[(size_t)rw * 128 + colb] = f2bf(acc[r] * s[r]);
        }
    }
}

// ---------------------------------------------------------------------------
// Fused layer: gather + relu-norm + GEMM, one wave per 16 nodes (disjoint).
//   h[m,:]  = relu( (sum_{j in in(m)} Tprev[col[j],:]) * inv_in[m] + bias )
//   if HAS_T: Tnext[m,:] = bf16( (h @ Wh) * inv_out[m] )   (128 cols)
//   P[m,:] += h @ Wo                                        (64 cols, fp32 RMW)
// Lane (m=lane&15, quad=lane>>4) gathers k-slices quad*8+kt*32..+7 -> exact
// MFMA A-fragment layout; 4x16B loads per edge per lane.
// ---------------------------------------------------------------------------
template <bool HAS_T>
__global__ __launch_bounds__(256) void fused_layer(
    const ushort_t* __restrict__ Tprev,  // [NN,128] bf16
    const int* __restrict__ row_ptr,
    const int* __restrict__ col,
    const float* __restrict__ inv_in,
    const float* __restrict__ bias,      // [128]
    const float* __restrict__ inv_out,
    const ushort_t* __restrict__ W1p,    // Wh packed (KF=4), used if HAS_T
    const ushort_t* __restrict__ W2p,    // Wout_l packed (KF=4)
    ushort_t* __restrict__ Tnext,
    float* __restrict__ P)
{
    const int lane = threadIdx.x & 63;
    const int w = threadIdx.x >> 6;
    const int row0 = blockIdx.x * 64 + w * 16;
    const int m = lane & 15;
    const int quad = lane >> 4;

    int node = row0 + m;
    int nclamp = node < NN ? node : NN - 1;
    int beg = row_ptr[nclamp];
    int cnt = row_ptr[nclamp + 1] - beg;

    const uint_t* T32 = (const uint_t*)Tprev;          // row = 64 uints
    // element offset of this lane's k-slice within a row (uints): quad*4 + kt*16
    float acc[4][8];
#pragma unroll
    for (int kt = 0; kt < 4; kt++)
#pragma unroll
        for (int i = 0; i < 8; i++) acc[kt][i] = 0.f;

    for (int j = 0; j < cnt; j++) {
        int c = col[beg + j];
        const uint_t* rp = T32 + (size_t)c * 64 + quad * 4;
        uint4 u0 = *(const uint4*)(rp);
        uint4 u1 = *(const uint4*)(rp + 16);
        uint4 u2 = *(const uint4*)(rp + 32);
        uint4 u3 = *(const uint4*)(rp + 48);
        uint_t q0[4] = {u0.x, u0.y, u0.z, u0.w};
        uint_t q1[4] = {u1.x, u1.y, u1.z, u1.w};
        uint_t q2[4] = {u2.x, u2.y, u2.z, u2.w};
        uint_t q3[4] = {u3.x, u3.y, u3.z, u3.w};
#pragma unroll
        for (int i = 0; i < 4; i++) {
            acc[0][2 * i] += bflo(q0[i]); acc[0][2 * i + 1] += bfhi(q0[i]);
            acc[1][2 * i] += bflo(q1[i]); acc[1][2 * i + 1] += bfhi(q1[i]);
            acc[2][2 * i] += bflo(q2[i]); acc[2][2 * i + 1] += bfhi(q2[i]);
            acc[3][2 * i] += bflo(q3[i]); acc[3][2 * i + 1] += bfhi(q3[i]);
        }
    }

    // epilogue of gather: h = relu(acc * inv_in + bias), pack to A-frags
    float s_in = inv_in[nclamp];
    sh8 a[4];
#pragma unroll
    for (int kt = 0; kt < 4; kt++) {
        float4 b0 = *(const float4*)(bias + quad * 8 + kt * 32);
        float4 b1 = *(const float4*)(bias + quad * 8 + kt * 32 + 4);
        float h[8];
        h[0] = fmaxf(fmaf(acc[kt][0], s_in, b0.x), 0.f);
        h[1] = fmaxf(fmaf(acc[kt][1], s_in, b0.y), 0.f);
        h[2] = fmaxf(fmaf(acc[kt][2], s_in, b0.z), 0.f);
        h[3] = fmaxf(fmaf(acc[kt][3], s_in, b0.w), 0.f);
        h[4] = fmaxf(fmaf(acc[kt][4], s_in, b1.x), 0.f);
        h[5] = fmaxf(fmaf(acc[kt][5], s_in, b1.y), 0.f);
        h[6] = fmaxf(fmaf(acc[kt][6], s_in, b1.z), 0.f);
        h[7] = fmaxf(fmaf(acc[kt][7], s_in, b1.w), 0.f);
        uint_t pk[4];
#pragma unroll
        for (int i = 0; i < 4; i++)
            pk[i] = (uint_t)f2bf(h[2 * i]) | ((uint_t)f2bf(h[2 * i + 1]) << 16);
        a[kt] = *(sh8*)pk;
    }

    // ---- GEMM: this wave's 16 rows, all output cols ----
    const int crow0 = row0 + quad * 4;
    if (HAS_T) {
        float so[4];
#pragma unroll
        for (int r = 0; r < 4; r++) {
            int rw = crow0 + r;
            so[r] = inv_out[rw < NN ? rw : NN - 1];
        }
#pragma unroll
        for (int ct = 0; ct < 8; ct++) {
            f4 c = {0.f, 0.f, 0.f, 0.f};
            const ushort_t* wp = W1p + ((size_t)(ct * 4) << 9) + lane * 8;
#pragma unroll
            for (int kt = 0; kt < 4; kt++)
                c = __builtin_amdgcn_mfma_f32_16x16x32_bf16(
                    a[kt], *(const sh8*)(wp + ((size_t)kt << 9)), c, 0, 0, 0);
            int colb = ct * 16 + m;
#pragma unroll
            for (int r = 0; r < 4; r++) {
                int rw = crow0 + r;
                if (rw < NN)
                    Tnext[(size_t)rw * 128 + colb] = f2bf(c[r] * so[r]);
            }
        }
    }
#pragma unroll
    for (int ct = 0; ct < 4; ct++) {
        f4 c = {0.f, 0.f, 0.f, 0.f};
        const ushort_t* wp = W2p + ((size_t)(ct * 4) << 9) + lane * 8;
#pragma unroll
        for (int kt = 0; kt < 4; kt++)
            c = __builtin_amdgcn_mfma_f32_16x16x32_bf16(
                a[kt], *(const sh8*)(wp + ((size_t)kt << 9)), c, 0, 0, 0);
        int colb = ct * 16 + m;
#pragma unroll
        for (int r = 0; r < 4; r++) {
            int rw = crow0 + r;
            if (rw < NN)
                P[(size_t)rw * 64 + colb] += c[r];
        }
    }
}

// bf16 final gather (D=64): out[node,:] = sum Pb[col[j],:] + bout   (fp32 out)
__global__ __launch_bounds__(256) void gather_out_kernel(
    const ushort_t* __restrict__ Pb,
    const int* __restrict__ row_ptr,
    const int* __restrict__ col,
    const float* __restrict__ bias,
    float* __restrict__ Y) {
    int idx = blockIdx.x * blockDim.x + threadIdx.x;
    int node = idx >> 3;
    int q = idx & 7;
    if (node >= NN) return;
    int beg = row_ptr[node];
    int end = row_ptr[node + 1];
    const uint_t* P32 = (const uint_t*)Pb;   // row = 32 uints
    float acc[8];
#pragma unroll
    for (int i = 0; i < 8; i++) acc[i] = 0.f;

    int j = beg;
    for (; j + 3 < end; j += 4) {
        int c0 = col[j], c1 = col[j + 1], c2 = col[j + 2], c3 = col[j + 3];
        uint4 u0 = *(const uint4*)(P32 + (size_t)c0 * 32 + q * 4);
        uint4 u1 = *(const uint4*)(P32 + (size_t)c1 * 32 + q * 4);
        uint4 u2 = *(const uint4*)(P32 + (size_t)c2 * 32 + q * 4);
        uint4 u3 = *(const uint4*)(P32 + (size_t)c3 * 32 + q * 4);
        uint_t w0[4] = {u0.x, u0.y, u0.z, u0.w};
        uint_t w1[4] = {u1.x, u1.y, u1.z, u1.w};
        uint_t w2[4] = {u2.x, u2.y, u2.z, u2.w};
        uint_t w3[4] = {u3.x, u3.y, u3.z, u3.w};
#pragma unroll
        for (int i = 0; i < 4; i++) {
            acc[2 * i] += (bflo(w0[i]) + bflo(w1[i])) + (bflo(w2[i]) + bflo(w3[i]));
            acc[2 * i + 1] += (bfhi(w0[i]) + bfhi(w1[i])) + (bfhi(w2[i]) + bfhi(w3[i]));
        }
    }
    for (; j < end; j++) {
        int c0 = col[j];
        uint4 u0 = *(const uint4*)(P32 + (size_t)c0 * 32 + q * 4);
        uint_t w0[4] = {u0.x, u0.y, u0.z, u0.w};
#pragma unroll
        for (int i = 0; i < 4; i++) {
            acc[2 * i] += bflo(w0[i]);
            acc[2 * i + 1] += bfhi(w0[i]);
        }
    }

    float4 o0, o1;
    o0.x = acc[0] + bias[q * 8 + 0];
    o0.y = acc[1] + bias[q * 8 + 1];
    o0.z = acc[2] + bias[q * 8 + 2];
    o0.w = acc[3] + bias[q * 8 + 3];
    o1.x = acc[4] + bias[q * 8 + 4];
    o1.y = acc[5] + bias[q * 8 + 5];
    o1.z = acc[6] + bias[q * 8 + 6];
    o1.w = acc[7] + bias[q * 8 + 7];
    *(float4*)(Y + (size_t)node * 64 + q * 8) = o0;
    *(float4*)(Y + (size_t)node * 64 + q * 8 + 4) = o1;
}

// ---------------------------------------------------------------------------
extern "C" void kernel_launch(void* const* d_in, const int* in_sizes, int n_in,
                              void* d_out, int out_size, void* d_ws, size_t ws_size,
                              hipStream_t stream) {
    const float* feats = (const float*)d_in[0];
    const int*   src   = (const int*)d_in[1];
    const int*   dst   = (const int*)d_in[2];
    const float* W0    = (const float*)d_in[3];
    const float* b0    = (const float*)d_in[4];
    const float* Wh    = (const float*)d_in[5];
    const float* bh    = (const float*)d_in[6];
    const float* Wout  = (const float*)d_in[7];
    const float* bout  = (const float*)d_in[8];
    float* out = (float*)d_out;

    float* ws      = (float*)d_ws;
    float* inv_out = ws;                              // NN
    float* inv_in  = ws + NN;                         // NN
    float* p       = ws + 2 * NN;                     // NN*64 fp32
    ushort_t* tba  = (ushort_t*)(p + (size_t)NN * 64);      // NN*128 bf16
    ushort_t* tbb  = tba + (size_t)NN * 128;          // NN*128 bf16
    ushort_t* fb   = tbb + (size_t)NN * 128;          // NN*256 bf16
    ushort_t* pb   = fb + (size_t)NN * 256;           // NN*64 bf16
    ushort_t* w0p  = pb + (size_t)NN * 64;            // 64*512
    ushort_t* whp  = w0p + 64 * 512;                  // 192*512
    ushort_t* wop  = whp + 192 * 512;                 // 112*512
    int* ibase     = (int*)(wop + 112 * 512);
    int* outdeg_i  = ibase;                           // NN
    int* indeg_i   = ibase + NN;                      // NN
    int* row_ptr   = ibase + 2 * NN;                  // NN+1
    int* cursor    = row_ptr + NN + 1;                // NN
    int* col       = cursor + NN;                     // NE

    const int B = 256;
    const int g0_blocks = (NN + 31) / 32;             // 938
    const int fused_blocks = (NN + 63) / 64;          // 469
    const int gout_blocks = (NN * 8 + B - 1) / B;

    // ---- CSR build + norms + conversions + packing ----
    hipMemsetAsync(outdeg_i, 0, 2 * NN * sizeof(int), stream);
    hipMemsetAsync(cursor, 0, NN * sizeof(int), stream);
    hipMemsetAsync(p, 0, (size_t)NN * D_OUT * sizeof(float), stream);
    degree_kernel<<<(NE + B - 1) / B, B, 0, stream>>>(src, dst, outdeg_i, indeg_i);
    rsqrt_kernel<<<(2 * NN + B - 1) / B, B, 0, stream>>>(outdeg_i, inv_out, 2 * NN);
    scan_kernel<<<1, 1024, 0, stream>>>(indeg_i, row_ptr);
    fill_kernel<<<(NE + B - 1) / B, B, 0, stream>>>(src, dst, row_ptr, cursor, col);
    featconv_kernel<<<(NN * D_IN / 8 + B - 1) / B, B, 0, stream>>>(feats, fb);
    packw_kernel<<<(368 * 64 + B - 1) / B, B, 0, stream>>>(W0, Wh, Wout, w0p, whp, wop);

    // ---- layer 0 GEMM: t0 = (feats @ W0) * inv_out ----
    gemm0_mfma<<<g0_blocks, 256, 0, stream>>>(fb, w0p, inv_out, tba);

    // ---- fused layers l=0..6: gather t_l -> h_l -> {t_{l+1}, p += h_l Wout_l}
    ushort_t* tcur = tba;
    ushort_t* tnext = tbb;
    for (int l = 0; l < NL; l++) {
        const float* bias_l = (l == 0) ? b0 : bh + (size_t)(l - 1) * D_H;
        fused_layer<true><<<fused_blocks, 256, 0, stream>>>(
            tcur, row_ptr, col, inv_in, bias_l, inv_out,
            whp + (size_t)l * 32 * 512, wop + (size_t)l * 16 * 512,
            tnext, p);
        ushort_t* tmp = tcur; tcur = tnext; tnext = tmp;
    }
    // l = 6: gather t_6 -> h_6, p += h_6 Wout_6 (no t output)
    fused_layer<false><<<fused_blocks, 256, 0, stream>>>(
        tcur, row_ptr, col, inv_in, bh + (size_t)(NL - 1) * D_H, inv_out,
        nullptr, wop + (size_t)NL * 16 * 512, nullptr, p);

    // ---- out = gather(bf16(p)) + bout ----
    pconv_kernel<<<(NN * D_OUT / 8 + B - 1) / B, B, 0, stream>>>(p, pb);
    gather_out_kernel<<<gout_blocks, B, 0, stream>>>(pb, row_ptr, col, bout, out);
}